// Round 16
// baseline (926.741 us; speedup 1.0000x reference)
//
#include <hip/hip_runtime.h>

#define N_NODES 100000
#define N_REL 4
#define N_EDGES 800000
#define HIDDEN 128
#define N_LAYERS 3

#define NBUCK 196   // ceil(100000/512) buckets of 512 nodes
#define NBB 196     // ceil(800000/4096) edge blocks
#define EPB 4096    // edges per bin block
#define BMAX 8192   // bucket_sort LDS staging capacity (mean 4082, std 64)

typedef __attribute__((ext_vector_type(8))) short short8;
typedef __attribute__((ext_vector_type(4))) float f32x4;

__device__ __forceinline__ unsigned short f2bf(float f) {
    unsigned u = __float_as_uint(f);
    u = (u + 0x7fffu + ((u >> 16) & 1u)) >> 16;
    return (unsigned short)u;
}
__device__ __forceinline__ float bf2f(unsigned short b) {
    return __uint_as_float(((unsigned)b) << 16);
}
// tanh(x) = 1 - 2/(e^{2x}+1), e = 2^(2*log2e*x). NaN-safe: e->inf => 1; e->0 => -1.
__device__ __forceinline__ float ftanh(float x) {
    float e = exp2f(2.8853900817779268f * x);
    return 1.0f - __fdividef(2.0f, e + 1.0f);
}

// ==================== CSR build: two-level bucketed counting sort ====================

__global__ __launch_bounds__(256) void bin_hist(const int* __restrict__ ei, int* __restrict__ bh) {
    __shared__ int hist[NBUCK];
    int r = blockIdx.y, blk = blockIdx.x, tid = threadIdx.x;
    for (int i = tid; i < NBUCK; i += 256) hist[i] = 0;
    __syncthreads();
    const int* dst = ei + (size_t)r * 2 * N_EDGES + N_EDGES;
#pragma unroll
    for (int i = 0; i < EPB / 256; ++i) {
        int e = blk * EPB + i * 256 + tid;
        if (e < N_EDGES) atomicAdd(&hist[dst[e] >> 9], 1);
    }
    __syncthreads();
    for (int i = tid; i < NBUCK; i += 256)
        bh[((size_t)r * NBUCK + i) * NBB + blk] = hist[i];
}

__global__ __launch_bounds__(256) void bin_scan(int* __restrict__ bh, int* __restrict__ btot) {
    __shared__ int sa[256], sb[256];
    int r = blockIdx.y, b = blockIdx.x, tid = threadIdx.x;
    int* row = bh + ((size_t)r * NBUCK + b) * NBB;
    int v = (tid < NBB) ? row[tid] : 0;
    sa[tid] = v;
    __syncthreads();
    int* pin = sa;
    int* pout = sb;
    for (int off = 1; off < 256; off <<= 1) {
        pout[tid] = pin[tid] + ((tid >= off) ? pin[tid - off] : 0);
        __syncthreads();
        int* t = pin; pin = pout; pout = t;
    }
    if (tid < NBB) row[tid] = pin[tid] - v;
    if (tid == NBB - 1) btot[r * NBUCK + b] = pin[tid];
}

__global__ void bin_base(const int* __restrict__ btot, int* __restrict__ bbase,
                         int* __restrict__ rowptr) {
    int r = threadIdx.x;
    if (r >= N_REL) return;
    int acc = 0;
    for (int b = 0; b < NBUCK; ++b) {
        bbase[r * (NBUCK + 1) + b] = acc;
        acc += btot[r * NBUCK + b];
    }
    bbase[r * (NBUCK + 1) + NBUCK] = acc;  // == N_EDGES
    rowptr[(size_t)r * (N_NODES + 1) + N_NODES] = N_EDGES;
}

__global__ __launch_bounds__(256) void bin_scatter(const int* __restrict__ ei,
                                                   const int* __restrict__ bh,
                                                   const int* __restrict__ bbase,
                                                   unsigned* __restrict__ staging) {
    __shared__ int hist[NBUCK];
    __shared__ int runStart[NBUCK + 1];
    __shared__ int runBaseG[NBUCK];
    __shared__ int curs[NBUCK];
    __shared__ unsigned packed[EPB];
    __shared__ int sa[256], sb[256];
    int r = blockIdx.y, blk = blockIdx.x, tid = threadIdx.x;
    const int* src = ei + (size_t)r * 2 * N_EDGES;
    const int* dst = src + N_EDGES;
    int e0 = blk * EPB;
    int ecnt = min(EPB, N_EDGES - e0);
    for (int i = tid; i < NBUCK; i += 256) hist[i] = 0;
    __syncthreads();
#pragma unroll
    for (int i = 0; i < EPB / 256; ++i) {
        int e = e0 + i * 256 + tid;
        if (e < N_EDGES) atomicAdd(&hist[dst[e] >> 9], 1);
    }
    __syncthreads();
    int v = (tid < NBUCK) ? hist[tid] : 0;
    sa[tid] = v;
    __syncthreads();
    int* pin = sa;
    int* pout = sb;
    for (int off = 1; off < 256; off <<= 1) {
        pout[tid] = pin[tid] + ((tid >= off) ? pin[tid - off] : 0);
        __syncthreads();
        int* t = pin; pin = pout; pout = t;
    }
    if (tid < NBUCK) {
        runStart[tid] = pin[tid] - v;
        curs[tid] = 0;
        runBaseG[tid] = bbase[r * (NBUCK + 1) + tid] + bh[((size_t)r * NBUCK + tid) * NBB + blk];
    }
    if (tid == 0) runStart[NBUCK] = ecnt;
    __syncthreads();
#pragma unroll
    for (int i = 0; i < EPB / 256; ++i) {
        int e = e0 + i * 256 + tid;
        if (e < N_EDGES) {
            int d = dst[e];
            int b = d >> 9;
            int lp = runStart[b] + atomicAdd(&curs[b], 1);
            packed[lp] = ((unsigned)(d & 511) << 17) | (unsigned)src[e];
        }
    }
    __syncthreads();
    for (int i = tid; i < ecnt; i += 256) {
        int lo = 0, hi = NBUCK;
        while (hi - lo > 1) {
            int mid = (lo + hi) >> 1;
            if (runStart[mid] <= i) lo = mid;
            else hi = mid;
        }
        staging[(size_t)r * N_EDGES + runBaseG[lo] + (i - runStart[lo])] = packed[i];
    }
}

__global__ __launch_bounds__(512) void bucket_sort(const unsigned* __restrict__ staging,
                                                   const int* __restrict__ bbase,
                                                   int* __restrict__ rowptr, int* __restrict__ cnt,
                                                   int* __restrict__ ssorted) {
    __shared__ int c512[512];
    __shared__ int lrp[512];
    __shared__ int curs[512];
    __shared__ int sb2[512];
    __shared__ int outbuf[BMAX];
    int r = blockIdx.y, b = blockIdx.x, tid = threadIdx.x;
    int base = bbase[r * (NBUCK + 1) + b];
    int total = bbase[r * (NBUCK + 1) + b + 1] - base;
    const unsigned* st = staging + (size_t)r * N_EDGES + base;
    c512[tid] = 0;
    __syncthreads();
    for (int i = tid; i < total; i += 512) atomicAdd(&c512[st[i] >> 17], 1);
    __syncthreads();
    int v = c512[tid];
    lrp[tid] = v;
    __syncthreads();
    int* pin = lrp;
    int* pout = sb2;
    for (int off = 1; off < 512; off <<= 1) {
        pout[tid] = pin[tid] + ((tid >= off) ? pin[tid - off] : 0);
        __syncthreads();
        int* t = pin; pin = pout; pout = t;
    }
    int excl = pin[tid] - v;
    __syncthreads();
    lrp[tid] = excl;
    curs[tid] = 0;
    int node = b * 512 + tid;
    if (node < N_NODES) {
        rowptr[(size_t)r * (N_NODES + 1) + node] = base + excl;
        cnt[(size_t)r * N_NODES + node] = v;
    }
    __syncthreads();
    if (total <= BMAX) {
        for (int i = tid; i < total; i += 512) {
            unsigned p = st[i];
            int dl = p >> 17;
            int pos = lrp[dl] + atomicAdd(&curs[dl], 1);
            outbuf[pos] = (int)(p & 0x1FFFFu);
        }
        __syncthreads();
        for (int i = tid; i < total; i += 512)
            ssorted[(size_t)r * N_EDGES + base + i] = outbuf[i];
    } else {
        for (int i = tid; i < total; i += 512) {
            unsigned p = st[i];
            int dl = p >> 17;
            int pos = lrp[dl] + atomicAdd(&curs[dl], 1);
            ssorted[(size_t)r * N_EDGES + base + pos] = (int)(p & 0x1FFFFu);
        }
    }
}

// ==================== dense pipeline ====================

__global__ void prepw_kernel(const float* __restrict__ Wbr, const float* __restrict__ Wcb,
                             unsigned short* __restrict__ WTh, unsigned short* __restrict__ WTl) {
    int t = blockIdx.x * blockDim.x + threadIdx.x;
    if (t >= 15 * HIDDEN * HIDDEN) return;
    int m = t >> 14;
    int j = (t >> 7) & 127;
    int k = t & 127;
    float v = (m < 12) ? Wbr[((size_t)m << 14) + k * HIDDEN + j]
                       : Wcb[((size_t)(m - 12) << 14) + k * HIDDEN + j];
    unsigned short hb = f2bf(v);
    WTh[t] = hb;
    WTl[t] = f2bf(v - bf2f(hb));
}

__global__ void hinit_kernel(const int* __restrict__ cnt, const float* __restrict__ Win,
                             unsigned short* __restrict__ hb) {
    int t = blockIdx.x * blockDim.x + threadIdx.x;
    if (t >= N_NODES * 16) return;
    int n = t >> 4, jq = (t & 15) * 8;
    float c0 = (float)cnt[n];
    float c1 = (float)cnt[N_NODES + n];
    float c2 = (float)cnt[2 * N_NODES + n];
    float c3 = (float)cnt[3 * N_NODES + n];
    short8 ob;
#pragma unroll
    for (int i = 0; i < 8; ++i) {
        int j = jq + i;
        float s = c0 * Win[j] + c1 * Win[HIDDEN + j] + c2 * Win[2 * HIDDEN + j] +
                  c3 * Win[3 * HIDDEN + j];
        ob[i] = (short)f2bf(ftanh(s));
    }
    *(short8*)(hb + (size_t)n * HIDDEN + jq) = ob;
}

// ---- gather: agg[r][n] = sum_{e in CSR row n of rel r} h[src[e]]; bf16 in/out ----
// ONE NODE PER WAVE: 64 lanes x 4B (2 bf16 cols) per edge row. Zero inter-node
// divergence (wave runs exactly its own degree); edge-list reads are wave-uniform
// (scalarizable). 4-edge unroll for load MLP.
__global__ __launch_bounds__(256) void gather_kernel(
    const int* __restrict__ rowptr, const int* __restrict__ ssorted,
    const unsigned short* __restrict__ hinb, unsigned short* __restrict__ agg) {
    const int r = blockIdx.y;
    const int node = blockIdx.x * 4 + (threadIdx.x >> 6);
    const int lane = threadIdx.x & 63;
    if (node >= N_NODES) return;
    const int* rp = rowptr + (size_t)r * (N_NODES + 1);
    int beg = rp[node], end = rp[node + 1];
    const int* ss = ssorted + (size_t)r * N_EDGES;
    float a0 = 0.f, a1 = 0.f;
    int e = beg;
    for (; e + 3 < end; e += 4) {
        int s0 = ss[e], s1 = ss[e + 1], s2 = ss[e + 2], s3 = ss[e + 3];
        unsigned v0 = *(const unsigned*)(hinb + (size_t)s0 * HIDDEN + lane * 2);
        unsigned v1 = *(const unsigned*)(hinb + (size_t)s1 * HIDDEN + lane * 2);
        unsigned v2 = *(const unsigned*)(hinb + (size_t)s2 * HIDDEN + lane * 2);
        unsigned v3 = *(const unsigned*)(hinb + (size_t)s3 * HIDDEN + lane * 2);
        a0 += (__uint_as_float(v0 << 16) + __uint_as_float(v1 << 16)) +
              (__uint_as_float(v2 << 16) + __uint_as_float(v3 << 16));
        a1 += (__uint_as_float(v0 & 0xffff0000u) + __uint_as_float(v1 & 0xffff0000u)) +
              (__uint_as_float(v2 & 0xffff0000u) + __uint_as_float(v3 & 0xffff0000u));
    }
    for (; e < end; ++e) {
        unsigned v0 = *(const unsigned*)(hinb + (size_t)ss[e] * HIDDEN + lane * 2);
        a0 += __uint_as_float(v0 << 16);
        a1 += __uint_as_float(v0 & 0xffff0000u);
    }
    unsigned pk = ((unsigned)f2bf(a0)) | (((unsigned)f2bf(a1)) << 16);
    *(unsigned*)(agg + ((size_t)r * N_NODES + node) * HIDDEN + lane * 2) = pk;
}

// ---- GEMM: h_out = tanh( (h_in + sum_r tanh(agg_r @ Wb_r)) @ Wc ), 64 nodes/block ----
// 512 threads, 8 waves = 8 COLUMN slices (16 cols each); weight fragments disjoint
// per wave; 4 relation tiles staged into 64 KB LDS behind ONE barrier.
__global__ __launch_bounds__(512) void gemm_kernel(
    const unsigned short* __restrict__ agg,         // [4][N][128] bf16
    const unsigned short* __restrict__ hinb,        // [N][128] bf16
    unsigned short* __restrict__ houtb,             // [N][128] bf16
    const unsigned short* __restrict__ WTbh,        // [4][128][128] bf16 hi, [col][k]
    const unsigned short* __restrict__ WTbl,        // [4][128][128] bf16 lo
    const unsigned short* __restrict__ WTch,        // [128][128] bf16 hi
    const unsigned short* __restrict__ WTcl) {      // [128][128] bf16 lo
    __shared__ unsigned short atile[4 * 64 * HIDDEN];  // 4 x 16 KB swizzled tiles
    const int tid = threadIdx.x;
    const int n0 = blockIdx.x * 64;
    const int lane = tid & 63;
    const int lrow = lane & 15;
    const int lk = lane >> 4;
    const int wv = tid >> 6;        // 0..7
    const int wcol = wv * 16;       // this wave's 16 output columns
    const int asw = (lrow & 7) << 4;

    const int gn = tid >> 3;        // staging: local node 0..63
    const int gq = tid & 7;         // staging: 32B chunk 0..7
    const int gnode = n0 + gn;
    const int grsw = (gn & 7) << 4;
    const bool gok = (gnode < N_NODES);

    // ---- stage ALL 4 relation tiles (swizzled); single barrier after ----
#pragma unroll
    for (int r = 0; r < N_REL; ++r) {
        const uint4* ap = (const uint4*)(agg + ((size_t)r * N_NODES + gnode) * HIDDEN) + gq * 2;
        uint4 s0 = gok ? ap[0] : uint4{0u, 0u, 0u, 0u};
        uint4 s1 = gok ? ap[1] : uint4{0u, 0u, 0u, 0u};
        char* tb = (char*)atile + r * 16384 + gn * 256;
        *(uint4*)(tb + ((gq * 32 + 0) ^ grsw)) = s0;
        *(uint4*)(tb + ((gq * 32 + 16) ^ grsw)) = s1;
    }

    // comb init (independent global loads; overlap with staging)
    float comb[4][4];
#pragma unroll
    for (int rt = 0; rt < 4; ++rt)
#pragma unroll
        for (int j = 0; j < 4; ++j) {
            int node = n0 + rt * 16 + lk * 4 + j;
            int col = wcol + lrow;
            comb[rt][j] = (node < N_NODES) ? bf2f(hinb[(size_t)node * HIDDEN + col]) : 0.f;
        }

    __syncthreads();

    // ---- 4 branch MFMA phases, barrier-free ----
#pragma unroll
    for (int r = 0; r < N_REL; ++r) {
        const unsigned short* Wh = WTbh + ((size_t)r << 14);
        const unsigned short* Wl = WTbl + ((size_t)r << 14);
        const char* tb = (const char*)atile + r * 16384;
        f32x4 macc[4];
#pragma unroll
        for (int rt = 0; rt < 4; ++rt) macc[rt] = f32x4{0.f, 0.f, 0.f, 0.f};
#pragma unroll
        for (int kb = 0; kb < 4; ++kb) {
            int wo = (wcol + lrow) * HIDDEN + kb * 32 + lk * 8;
            short8 bh = *(const short8*)(Wh + wo);
            short8 bl = *(const short8*)(Wl + wo);
#pragma unroll
            for (int rt = 0; rt < 4; ++rt) {
                int ao = (rt * 16 + lrow) * 256 + ((kb * 64 + lk * 16) ^ asw);
                short8 ah = *(const short8*)(tb + ao);
                macc[rt] = __builtin_amdgcn_mfma_f32_16x16x32_bf16(ah, bh, macc[rt], 0, 0, 0);
                macc[rt] = __builtin_amdgcn_mfma_f32_16x16x32_bf16(ah, bl, macc[rt], 0, 0, 0);
            }
        }
#pragma unroll
        for (int rt = 0; rt < 4; ++rt)
#pragma unroll
            for (int j = 0; j < 4; ++j) comb[rt][j] += ftanh(macc[rt][j]);
    }

    // ---- combine: comb -> hi tile only (tile 0), swizzled ----
    __syncthreads();
#pragma unroll
    for (int rt = 0; rt < 4; ++rt)
#pragma unroll
        for (int j = 0; j < 4; ++j) {
            int row = rt * 16 + lk * 4 + j;
            int col = wcol + lrow;
            int byt = row * 256 + ((col * 2) ^ ((row & 7) << 4));
            *(unsigned short*)((char*)atile + byt) = f2bf(comb[rt][j]);
        }
    __syncthreads();

    f32x4 macc[4];
#pragma unroll
    for (int rt = 0; rt < 4; ++rt) macc[rt] = f32x4{0.f, 0.f, 0.f, 0.f};
#pragma unroll
    for (int kb = 0; kb < 4; ++kb) {
        int wo = (wcol + lrow) * HIDDEN + kb * 32 + lk * 8;
        short8 bh = *(const short8*)(WTch + wo);
        short8 bl = *(const short8*)(WTcl + wo);
#pragma unroll
        for (int rt = 0; rt < 4; ++rt) {
            int ao = (rt * 16 + lrow) * 256 + ((kb * 64 + lk * 16) ^ asw);
            short8 ah = *(const short8*)((const char*)atile + ao);
            macc[rt] = __builtin_amdgcn_mfma_f32_16x16x32_bf16(ah, bh, macc[rt], 0, 0, 0);
            macc[rt] = __builtin_amdgcn_mfma_f32_16x16x32_bf16(ah, bl, macc[rt], 0, 0, 0);
        }
    }
#pragma unroll
    for (int rt = 0; rt < 4; ++rt)
#pragma unroll
        for (int j = 0; j < 4; ++j) {
            int node = n0 + rt * 16 + lk * 4 + j;
            if (node < N_NODES)
                houtb[(size_t)node * HIDDEN + wcol + lrow] = f2bf(ftanh(macc[rt][j]));
        }
}

// ---- out[j] = sum_n h[n][j] (bf16 in, f32 out) ----
__global__ void reduce_kernel(const unsigned short* __restrict__ h, float* __restrict__ out) {
    int j = threadIdx.x;
    float s = 0.f;
    for (int n = blockIdx.x; n < N_NODES; n += gridDim.x)
        s += bf2f(h[(size_t)n * HIDDEN + j]);
    atomicAdd(&out[j], s);
}

extern "C" void kernel_launch(void* const* d_in, const int* in_sizes, int n_in,
                              void* d_out, int out_size, void* d_ws, size_t ws_size,
                              hipStream_t stream) {
    const int* ei = (const int*)d_in[0];
    const float* Win = (const float*)d_in[1];
    const float* Wbr = (const float*)d_in[2];
    const float* Wcb = (const float*)d_in[3];
    float* out = (float*)d_out;

    char* p = (char*)d_ws;
    auto alloc = [&](size_t bytes) {
        char* q = p;
        p += (bytes + 511) & ~(size_t)511;
        return q;
    };
    int* cnt = (int*)alloc((size_t)N_REL * N_NODES * 4);
    int* rowptr = (int*)alloc((size_t)N_REL * (N_NODES + 1) * 4);
    int* ssorted = (int*)alloc((size_t)N_REL * N_EDGES * 4);
    unsigned* staging = (unsigned*)alloc((size_t)N_REL * N_EDGES * 4);
    int* bh = (int*)alloc((size_t)N_REL * NBUCK * NBB * 4);
    int* btot = (int*)alloc((size_t)N_REL * NBUCK * 4);
    int* bbase = (int*)alloc((size_t)N_REL * (NBUCK + 1) * 4);
    unsigned short* WTh = (unsigned short*)alloc((size_t)15 * HIDDEN * HIDDEN * 2);
    unsigned short* WTl = (unsigned short*)alloc((size_t)15 * HIDDEN * HIDDEN * 2);
    unsigned short* hb0 = (unsigned short*)alloc((size_t)N_NODES * HIDDEN * 2);
    unsigned short* hb1 = (unsigned short*)alloc((size_t)N_NODES * HIDDEN * 2);
    unsigned short* agg = (unsigned short*)alloc((size_t)N_REL * N_NODES * HIDDEN * 2);

    // ---- CSR build (bucketed counting sort; also emits cnt = degrees) ----
    dim3 bg(NBB, N_REL);
    bin_hist<<<bg, 256, 0, stream>>>(ei, bh);
    dim3 sg(NBUCK, N_REL);
    bin_scan<<<sg, 256, 0, stream>>>(bh, btot);
    bin_base<<<1, 64, 0, stream>>>(btot, bbase, rowptr);
    bin_scatter<<<bg, 256, 0, stream>>>(ei, bh, bbase, staging);
    bucket_sort<<<sg, 512, 0, stream>>>(staging, bbase, rowptr, cnt, ssorted);

    // ---- weights + h0 ----
    prepw_kernel<<<(15 * HIDDEN * HIDDEN + 255) / 256, 256, 0, stream>>>(Wbr, Wcb, WTh, WTl);
    hinit_kernel<<<(N_NODES * 16 + 255) / 256, 256, 0, stream>>>(cnt, Win, hb0);

    // ---- layers: gather (per relation) + fused GEMM ----
    dim3 gg((N_NODES + 3) / 4, N_REL);
    int cgrid = (N_NODES + 63) / 64;
    unsigned short* hbio[2] = {hb0, hb1};
    for (int l = 0; l < N_LAYERS; ++l) {
        int a = l & 1, b = a ^ 1;
        gather_kernel<<<gg, 256, 0, stream>>>(rowptr, ssorted, hbio[a], agg);
        gemm_kernel<<<cgrid, 512, 0, stream>>>(
            agg, hbio[a], hbio[b],
            WTh + (size_t)(l * 4) * HIDDEN * HIDDEN, WTl + (size_t)(l * 4) * HIDDEN * HIDDEN,
            WTh + (size_t)(12 + l) * HIDDEN * HIDDEN, WTl + (size_t)(12 + l) * HIDDEN * HIDDEN);
    }
    unsigned short* hfin = hbio[N_LAYERS & 1];

    hipMemsetAsync(out, 0, HIDDEN * sizeof(float), stream);
    reduce_kernel<<<1024, HIDDEN, 0, stream>>>(hfin, out);
}

// Round 17
// 849.345 us; speedup vs baseline: 1.0911x; 1.0911x over previous
//
#include <hip/hip_runtime.h>

#define N_NODES 100000
#define N_REL 4
#define N_EDGES 800000
#define HIDDEN 128
#define N_LAYERS 3

#define NBUCK 196   // ceil(100000/512) buckets of 512 nodes
#define NBB 196     // ceil(800000/4096) edge blocks
#define EPB 4096    // edges per bin block
#define BMAX 8192   // bucket_sort LDS staging capacity (mean 4082, std 64)
#define PERMN (NBUCK * 512)  // 100352 perm slots per relation

typedef __attribute__((ext_vector_type(8))) short short8;
typedef __attribute__((ext_vector_type(4))) float f32x4;

__device__ __forceinline__ unsigned short f2bf(float f) {
    unsigned u = __float_as_uint(f);
    u = (u + 0x7fffu + ((u >> 16) & 1u)) >> 16;
    return (unsigned short)u;
}
__device__ __forceinline__ float bf2f(unsigned short b) {
    return __uint_as_float(((unsigned)b) << 16);
}
// tanh(x) = 1 - 2/(e^{2x}+1), e = 2^(2*log2e*x). NaN-safe: e->inf => 1; e->0 => -1.
__device__ __forceinline__ float ftanh(float x) {
    float e = exp2f(2.8853900817779268f * x);
    return 1.0f - __fdividef(2.0f, e + 1.0f);
}

// ==================== CSR build: two-level bucketed counting sort ====================

__global__ __launch_bounds__(256) void bin_hist(const int* __restrict__ ei, int* __restrict__ bh) {
    __shared__ int hist[NBUCK];
    int r = blockIdx.y, blk = blockIdx.x, tid = threadIdx.x;
    for (int i = tid; i < NBUCK; i += 256) hist[i] = 0;
    __syncthreads();
    const int* dst = ei + (size_t)r * 2 * N_EDGES + N_EDGES;
#pragma unroll
    for (int i = 0; i < EPB / 256; ++i) {
        int e = blk * EPB + i * 256 + tid;
        if (e < N_EDGES) atomicAdd(&hist[dst[e] >> 9], 1);
    }
    __syncthreads();
    for (int i = tid; i < NBUCK; i += 256)
        bh[((size_t)r * NBUCK + i) * NBB + blk] = hist[i];
}

__global__ __launch_bounds__(256) void bin_scan(int* __restrict__ bh, int* __restrict__ btot) {
    __shared__ int sa[256], sb[256];
    int r = blockIdx.y, b = blockIdx.x, tid = threadIdx.x;
    int* row = bh + ((size_t)r * NBUCK + b) * NBB;
    int v = (tid < NBB) ? row[tid] : 0;
    sa[tid] = v;
    __syncthreads();
    int* pin = sa;
    int* pout = sb;
    for (int off = 1; off < 256; off <<= 1) {
        pout[tid] = pin[tid] + ((tid >= off) ? pin[tid - off] : 0);
        __syncthreads();
        int* t = pin; pin = pout; pout = t;
    }
    if (tid < NBB) row[tid] = pin[tid] - v;
    if (tid == NBB - 1) btot[r * NBUCK + b] = pin[tid];
}

__global__ void bin_base(const int* __restrict__ btot, int* __restrict__ bbase,
                         int* __restrict__ rowptr) {
    int r = threadIdx.x;
    if (r >= N_REL) return;
    int acc = 0;
    for (int b = 0; b < NBUCK; ++b) {
        bbase[r * (NBUCK + 1) + b] = acc;
        acc += btot[r * NBUCK + b];
    }
    bbase[r * (NBUCK + 1) + NBUCK] = acc;  // == N_EDGES
    rowptr[(size_t)r * (N_NODES + 1) + N_NODES] = N_EDGES;
}

__global__ __launch_bounds__(256) void bin_scatter(const int* __restrict__ ei,
                                                   const int* __restrict__ bh,
                                                   const int* __restrict__ bbase,
                                                   unsigned* __restrict__ staging) {
    __shared__ int hist[NBUCK];
    __shared__ int runStart[NBUCK + 1];
    __shared__ int runBaseG[NBUCK];
    __shared__ int curs[NBUCK];
    __shared__ unsigned packed[EPB];
    __shared__ int sa[256], sb[256];
    int r = blockIdx.y, blk = blockIdx.x, tid = threadIdx.x;
    const int* src = ei + (size_t)r * 2 * N_EDGES;
    const int* dst = src + N_EDGES;
    int e0 = blk * EPB;
    int ecnt = min(EPB, N_EDGES - e0);
    for (int i = tid; i < NBUCK; i += 256) hist[i] = 0;
    __syncthreads();
#pragma unroll
    for (int i = 0; i < EPB / 256; ++i) {
        int e = e0 + i * 256 + tid;
        if (e < N_EDGES) atomicAdd(&hist[dst[e] >> 9], 1);
    }
    __syncthreads();
    int v = (tid < NBUCK) ? hist[tid] : 0;
    sa[tid] = v;
    __syncthreads();
    int* pin = sa;
    int* pout = sb;
    for (int off = 1; off < 256; off <<= 1) {
        pout[tid] = pin[tid] + ((tid >= off) ? pin[tid - off] : 0);
        __syncthreads();
        int* t = pin; pin = pout; pout = t;
    }
    if (tid < NBUCK) {
        runStart[tid] = pin[tid] - v;
        curs[tid] = 0;
        runBaseG[tid] = bbase[r * (NBUCK + 1) + tid] + bh[((size_t)r * NBUCK + tid) * NBB + blk];
    }
    if (tid == 0) runStart[NBUCK] = ecnt;
    __syncthreads();
#pragma unroll
    for (int i = 0; i < EPB / 256; ++i) {
        int e = e0 + i * 256 + tid;
        if (e < N_EDGES) {
            int d = dst[e];
            int b = d >> 9;
            int lp = runStart[b] + atomicAdd(&curs[b], 1);
            packed[lp] = ((unsigned)(d & 511) << 17) | (unsigned)src[e];
        }
    }
    __syncthreads();
    for (int i = tid; i < ecnt; i += 256) {
        int lo = 0, hi = NBUCK;
        while (hi - lo > 1) {
            int mid = (lo + hi) >> 1;
            if (runStart[mid] <= i) lo = mid;
            else hi = mid;
        }
        staging[(size_t)r * N_EDGES + runBaseG[lo] + (i - runStart[lo])] = packed[i];
    }
}

// per-bucket counting sort by exact dst; emits rowptr, cnt, coalesced ssorted,
// and a degree-sorted node permutation (for divergence-free gather waves).
__global__ __launch_bounds__(512) void bucket_sort(const unsigned* __restrict__ staging,
                                                   const int* __restrict__ bbase,
                                                   int* __restrict__ rowptr, int* __restrict__ cnt,
                                                   int* __restrict__ ssorted,
                                                   int* __restrict__ perm) {
    __shared__ int c512[512];
    __shared__ int lrp[512];
    __shared__ int curs[512];
    __shared__ int sb2[512];
    __shared__ int outbuf[BMAX];
    __shared__ int dh[32], dbase[32], dcur[32];
    int r = blockIdx.y, b = blockIdx.x, tid = threadIdx.x;
    int base = bbase[r * (NBUCK + 1) + b];
    int total = bbase[r * (NBUCK + 1) + b + 1] - base;
    const unsigned* st = staging + (size_t)r * N_EDGES + base;
    c512[tid] = 0;
    if (tid < 32) { dh[tid] = 0; dcur[tid] = 0; }
    __syncthreads();
    for (int i = tid; i < total; i += 512) atomicAdd(&c512[st[i] >> 17], 1);
    __syncthreads();
    int v = c512[tid];
    lrp[tid] = v;
    // degree histogram (capped at 31) for within-bucket degree sort
    int dbin = min(v, 31);
    atomicAdd(&dh[dbin], 1);
    __syncthreads();
    if (tid == 0) {
        int acc = 0;
        for (int i = 0; i < 32; ++i) { dbase[i] = acc; acc += dh[i]; }
    }
    int* pin = lrp;
    int* pout = sb2;
    for (int off = 1; off < 512; off <<= 1) {
        pout[tid] = pin[tid] + ((tid >= off) ? pin[tid - off] : 0);
        __syncthreads();
        int* t = pin; pin = pout; pout = t;
    }
    int excl = pin[tid] - v;
    __syncthreads();
    lrp[tid] = excl;
    curs[tid] = 0;
    int node = b * 512 + tid;
    if (node < N_NODES) {
        rowptr[(size_t)r * (N_NODES + 1) + node] = base + excl;
        cnt[(size_t)r * N_NODES + node] = v;
    }
    // degree-sorted permutation: perm[r][b*512 + rank] = node
    {
        int pos = dbase[dbin] + atomicAdd(&dcur[dbin], 1);
        perm[(size_t)r * PERMN + b * 512 + pos] = node;
    }
    __syncthreads();
    if (total <= BMAX) {
        for (int i = tid; i < total; i += 512) {
            unsigned p = st[i];
            int dl = p >> 17;
            int pos = lrp[dl] + atomicAdd(&curs[dl], 1);
            outbuf[pos] = (int)(p & 0x1FFFFu);
        }
        __syncthreads();
        for (int i = tid; i < total; i += 512)
            ssorted[(size_t)r * N_EDGES + base + i] = outbuf[i];
    } else {
        for (int i = tid; i < total; i += 512) {
            unsigned p = st[i];
            int dl = p >> 17;
            int pos = lrp[dl] + atomicAdd(&curs[dl], 1);
            ssorted[(size_t)r * N_EDGES + base + pos] = (int)(p & 0x1FFFFu);
        }
    }
}

// ==================== dense pipeline ====================

__global__ void prepw_kernel(const float* __restrict__ Wbr, const float* __restrict__ Wcb,
                             unsigned short* __restrict__ WTh, unsigned short* __restrict__ WTl) {
    int t = blockIdx.x * blockDim.x + threadIdx.x;
    if (t >= 15 * HIDDEN * HIDDEN) return;
    int m = t >> 14;
    int j = (t >> 7) & 127;
    int k = t & 127;
    float v = (m < 12) ? Wbr[((size_t)m << 14) + k * HIDDEN + j]
                       : Wcb[((size_t)(m - 12) << 14) + k * HIDDEN + j];
    unsigned short hb = f2bf(v);
    WTh[t] = hb;
    WTl[t] = f2bf(v - bf2f(hb));
}

__global__ void hinit_kernel(const int* __restrict__ cnt, const float* __restrict__ Win,
                             unsigned short* __restrict__ hb) {
    int t = blockIdx.x * blockDim.x + threadIdx.x;
    if (t >= N_NODES * 16) return;
    int n = t >> 4, jq = (t & 15) * 8;
    float c0 = (float)cnt[n];
    float c1 = (float)cnt[N_NODES + n];
    float c2 = (float)cnt[2 * N_NODES + n];
    float c3 = (float)cnt[3 * N_NODES + n];
    short8 ob;
#pragma unroll
    for (int i = 0; i < 8; ++i) {
        int j = jq + i;
        float s = c0 * Win[j] + c1 * Win[HIDDEN + j] + c2 * Win[2 * HIDDEN + j] +
                  c3 * Win[3 * HIDDEN + j];
        ob[i] = (short)f2bf(ftanh(s));
    }
    *(short8*)(hb + (size_t)n * HIDDEN + jq) = ob;
}

// ---- gather: agg[r][n] = sum_{e in CSR row n of rel r} h[src[e]]; bf16 in/out ----
// R15 structure (16 lanes/node x 4 nodes/wave x 4-edge unroll = 16 loads in flight)
// + degree-sorted node order via perm: the 4 nodes in a wave have ~equal degree,
// eliminating max-degree divergence without touching MLP.
__global__ __launch_bounds__(256) void gather_kernel(
    const int* __restrict__ rowptr, const int* __restrict__ ssorted,
    const int* __restrict__ perm,
    const unsigned short* __restrict__ hinb, unsigned short* __restrict__ agg) {
    const int r = blockIdx.y;
    const int gidx = blockIdx.x * 16 + (threadIdx.x >> 4);
    const int l16 = threadIdx.x & 15;
    const int node = perm[(size_t)r * PERMN + gidx];
    if (node >= N_NODES) return;
    const int* rp = rowptr + (size_t)r * (N_NODES + 1);
    int beg = rp[node], end = rp[node + 1];
    const int* ss = ssorted + (size_t)r * N_EDGES;
    float acc[8];
#pragma unroll
    for (int i = 0; i < 8; ++i) acc[i] = 0.f;
    int e = beg;
    for (; e + 3 < end; e += 4) {
        int s0 = ss[e], s1 = ss[e + 1], s2 = ss[e + 2], s3 = ss[e + 3];
        uint4 v0 = *((const uint4*)(hinb + (size_t)s0 * HIDDEN) + l16);
        uint4 v1 = *((const uint4*)(hinb + (size_t)s1 * HIDDEN) + l16);
        uint4 v2 = *((const uint4*)(hinb + (size_t)s2 * HIDDEN) + l16);
        uint4 v3 = *((const uint4*)(hinb + (size_t)s3 * HIDDEN) + l16);
        unsigned a0[4] = {v0.x, v0.y, v0.z, v0.w};
        unsigned a1[4] = {v1.x, v1.y, v1.z, v1.w};
        unsigned a2[4] = {v2.x, v2.y, v2.z, v2.w};
        unsigned a3[4] = {v3.x, v3.y, v3.z, v3.w};
#pragma unroll
        for (int c = 0; c < 4; ++c) {
            acc[c * 2] += (__uint_as_float(a0[c] << 16) + __uint_as_float(a1[c] << 16)) +
                          (__uint_as_float(a2[c] << 16) + __uint_as_float(a3[c] << 16));
            acc[c * 2 + 1] +=
                (__uint_as_float(a0[c] & 0xffff0000u) + __uint_as_float(a1[c] & 0xffff0000u)) +
                (__uint_as_float(a2[c] & 0xffff0000u) + __uint_as_float(a3[c] & 0xffff0000u));
        }
    }
    for (; e < end; ++e) {
        int s0 = ss[e];
        uint4 v0 = *((const uint4*)(hinb + (size_t)s0 * HIDDEN) + l16);
        unsigned a0[4] = {v0.x, v0.y, v0.z, v0.w};
#pragma unroll
        for (int c = 0; c < 4; ++c) {
            acc[c * 2] += __uint_as_float(a0[c] << 16);
            acc[c * 2 + 1] += __uint_as_float(a0[c] & 0xffff0000u);
        }
    }
    short8 pk;
#pragma unroll
    for (int c = 0; c < 8; ++c) pk[c] = (short)f2bf(acc[c]);
    *(short8*)(agg + ((size_t)r * N_NODES + node) * HIDDEN + l16 * 8) = pk;
}

// ---- GEMM: h_out = tanh( (h_in + sum_r tanh(agg_r @ Wb_r)) @ Wc ), 64 nodes/block ----
// 512 threads, 8 waves = 8 COLUMN slices (16 cols each); weight fragments disjoint
// per wave; 4 relation tiles staged into 64 KB LDS behind ONE barrier.
__global__ __launch_bounds__(512) void gemm_kernel(
    const unsigned short* __restrict__ agg,         // [4][N][128] bf16
    const unsigned short* __restrict__ hinb,        // [N][128] bf16
    unsigned short* __restrict__ houtb,             // [N][128] bf16
    const unsigned short* __restrict__ WTbh,        // [4][128][128] bf16 hi, [col][k]
    const unsigned short* __restrict__ WTbl,        // [4][128][128] bf16 lo
    const unsigned short* __restrict__ WTch,        // [128][128] bf16 hi
    const unsigned short* __restrict__ WTcl) {      // [128][128] bf16 lo
    __shared__ unsigned short atile[4 * 64 * HIDDEN];  // 4 x 16 KB swizzled tiles
    const int tid = threadIdx.x;
    const int n0 = blockIdx.x * 64;
    const int lane = tid & 63;
    const int lrow = lane & 15;
    const int lk = lane >> 4;
    const int wv = tid >> 6;        // 0..7
    const int wcol = wv * 16;       // this wave's 16 output columns
    const int asw = (lrow & 7) << 4;

    const int gn = tid >> 3;        // staging: local node 0..63
    const int gq = tid & 7;         // staging: 32B chunk 0..7
    const int gnode = n0 + gn;
    const int grsw = (gn & 7) << 4;
    const bool gok = (gnode < N_NODES);

    // ---- stage ALL 4 relation tiles (swizzled); single barrier after ----
#pragma unroll
    for (int r = 0; r < N_REL; ++r) {
        const uint4* ap = (const uint4*)(agg + ((size_t)r * N_NODES + gnode) * HIDDEN) + gq * 2;
        uint4 s0 = gok ? ap[0] : uint4{0u, 0u, 0u, 0u};
        uint4 s1 = gok ? ap[1] : uint4{0u, 0u, 0u, 0u};
        char* tb = (char*)atile + r * 16384 + gn * 256;
        *(uint4*)(tb + ((gq * 32 + 0) ^ grsw)) = s0;
        *(uint4*)(tb + ((gq * 32 + 16) ^ grsw)) = s1;
    }

    // comb init (independent global loads; overlap with staging)
    float comb[4][4];
#pragma unroll
    for (int rt = 0; rt < 4; ++rt)
#pragma unroll
        for (int j = 0; j < 4; ++j) {
            int node = n0 + rt * 16 + lk * 4 + j;
            int col = wcol + lrow;
            comb[rt][j] = (node < N_NODES) ? bf2f(hinb[(size_t)node * HIDDEN + col]) : 0.f;
        }

    __syncthreads();

    // ---- 4 branch MFMA phases, barrier-free ----
#pragma unroll
    for (int r = 0; r < N_REL; ++r) {
        const unsigned short* Wh = WTbh + ((size_t)r << 14);
        const unsigned short* Wl = WTbl + ((size_t)r << 14);
        const char* tb = (const char*)atile + r * 16384;
        f32x4 macc[4];
#pragma unroll
        for (int rt = 0; rt < 4; ++rt) macc[rt] = f32x4{0.f, 0.f, 0.f, 0.f};
#pragma unroll
        for (int kb = 0; kb < 4; ++kb) {
            int wo = (wcol + lrow) * HIDDEN + kb * 32 + lk * 8;
            short8 bh = *(const short8*)(Wh + wo);
            short8 bl = *(const short8*)(Wl + wo);
#pragma unroll
            for (int rt = 0; rt < 4; ++rt) {
                int ao = (rt * 16 + lrow) * 256 + ((kb * 64 + lk * 16) ^ asw);
                short8 ah = *(const short8*)(tb + ao);
                macc[rt] = __builtin_amdgcn_mfma_f32_16x16x32_bf16(ah, bh, macc[rt], 0, 0, 0);
                macc[rt] = __builtin_amdgcn_mfma_f32_16x16x32_bf16(ah, bl, macc[rt], 0, 0, 0);
            }
        }
#pragma unroll
        for (int rt = 0; rt < 4; ++rt)
#pragma unroll
            for (int j = 0; j < 4; ++j) comb[rt][j] += ftanh(macc[rt][j]);
    }

    // ---- combine: comb -> hi tile only (tile 0), swizzled ----
    __syncthreads();
#pragma unroll
    for (int rt = 0; rt < 4; ++rt)
#pragma unroll
        for (int j = 0; j < 4; ++j) {
            int row = rt * 16 + lk * 4 + j;
            int col = wcol + lrow;
            int byt = row * 256 + ((col * 2) ^ ((row & 7) << 4));
            *(unsigned short*)((char*)atile + byt) = f2bf(comb[rt][j]);
        }
    __syncthreads();

    f32x4 macc[4];
#pragma unroll
    for (int rt = 0; rt < 4; ++rt) macc[rt] = f32x4{0.f, 0.f, 0.f, 0.f};
#pragma unroll
    for (int kb = 0; kb < 4; ++kb) {
        int wo = (wcol + lrow) * HIDDEN + kb * 32 + lk * 8;
        short8 bh = *(const short8*)(WTch + wo);
        short8 bl = *(const short8*)(WTcl + wo);
#pragma unroll
        for (int rt = 0; rt < 4; ++rt) {
            int ao = (rt * 16 + lrow) * 256 + ((kb * 64 + lk * 16) ^ asw);
            short8 ah = *(const short8*)((const char*)atile + ao);
            macc[rt] = __builtin_amdgcn_mfma_f32_16x16x32_bf16(ah, bh, macc[rt], 0, 0, 0);
            macc[rt] = __builtin_amdgcn_mfma_f32_16x16x32_bf16(ah, bl, macc[rt], 0, 0, 0);
        }
    }
#pragma unroll
    for (int rt = 0; rt < 4; ++rt)
#pragma unroll
        for (int j = 0; j < 4; ++j) {
            int node = n0 + rt * 16 + lk * 4 + j;
            if (node < N_NODES)
                houtb[(size_t)node * HIDDEN + wcol + lrow] = f2bf(ftanh(macc[rt][j]));
        }
}

// ---- out[j] = sum_n h[n][j] (bf16 in, f32 out) ----
__global__ void reduce_kernel(const unsigned short* __restrict__ h, float* __restrict__ out) {
    int j = threadIdx.x;
    float s = 0.f;
    for (int n = blockIdx.x; n < N_NODES; n += gridDim.x)
        s += bf2f(h[(size_t)n * HIDDEN + j]);
    atomicAdd(&out[j], s);
}

extern "C" void kernel_launch(void* const* d_in, const int* in_sizes, int n_in,
                              void* d_out, int out_size, void* d_ws, size_t ws_size,
                              hipStream_t stream) {
    const int* ei = (const int*)d_in[0];
    const float* Win = (const float*)d_in[1];
    const float* Wbr = (const float*)d_in[2];
    const float* Wcb = (const float*)d_in[3];
    float* out = (float*)d_out;

    char* p = (char*)d_ws;
    auto alloc = [&](size_t bytes) {
        char* q = p;
        p += (bytes + 511) & ~(size_t)511;
        return q;
    };
    int* cnt = (int*)alloc((size_t)N_REL * N_NODES * 4);
    int* rowptr = (int*)alloc((size_t)N_REL * (N_NODES + 1) * 4);
    int* ssorted = (int*)alloc((size_t)N_REL * N_EDGES * 4);
    unsigned* staging = (unsigned*)alloc((size_t)N_REL * N_EDGES * 4);
    int* bh = (int*)alloc((size_t)N_REL * NBUCK * NBB * 4);
    int* btot = (int*)alloc((size_t)N_REL * NBUCK * 4);
    int* bbase = (int*)alloc((size_t)N_REL * (NBUCK + 1) * 4);
    int* perm = (int*)alloc((size_t)N_REL * PERMN * 4);
    unsigned short* WTh = (unsigned short*)alloc((size_t)15 * HIDDEN * HIDDEN * 2);
    unsigned short* WTl = (unsigned short*)alloc((size_t)15 * HIDDEN * HIDDEN * 2);
    unsigned short* hb0 = (unsigned short*)alloc((size_t)N_NODES * HIDDEN * 2);
    unsigned short* hb1 = (unsigned short*)alloc((size_t)N_NODES * HIDDEN * 2);
    unsigned short* agg = (unsigned short*)alloc((size_t)N_REL * N_NODES * HIDDEN * 2);

    // ---- CSR build (bucketed counting sort; also emits cnt = degrees, perm) ----
    dim3 bg(NBB, N_REL);
    bin_hist<<<bg, 256, 0, stream>>>(ei, bh);
    dim3 sg(NBUCK, N_REL);
    bin_scan<<<sg, 256, 0, stream>>>(bh, btot);
    bin_base<<<1, 64, 0, stream>>>(btot, bbase, rowptr);
    bin_scatter<<<bg, 256, 0, stream>>>(ei, bh, bbase, staging);
    bucket_sort<<<sg, 512, 0, stream>>>(staging, bbase, rowptr, cnt, ssorted, perm);

    // ---- weights + h0 ----
    prepw_kernel<<<(15 * HIDDEN * HIDDEN + 255) / 256, 256, 0, stream>>>(Wbr, Wcb, WTh, WTl);
    hinit_kernel<<<(N_NODES * 16 + 255) / 256, 256, 0, stream>>>(cnt, Win, hb0);

    // ---- layers: gather (per relation) + fused GEMM ----
    dim3 gg(PERMN / 16, N_REL);
    int cgrid = (N_NODES + 63) / 64;
    unsigned short* hbio[2] = {hb0, hb1};
    for (int l = 0; l < N_LAYERS; ++l) {
        int a = l & 1, b = a ^ 1;
        gather_kernel<<<gg, 256, 0, stream>>>(rowptr, ssorted, perm, hbio[a], agg);
        gemm_kernel<<<cgrid, 512, 0, stream>>>(
            agg, hbio[a], hbio[b],
            WTh + (size_t)(l * 4) * HIDDEN * HIDDEN, WTl + (size_t)(l * 4) * HIDDEN * HIDDEN,
            WTh + (size_t)(12 + l) * HIDDEN * HIDDEN, WTl + (size_t)(12 + l) * HIDDEN * HIDDEN);
    }
    unsigned short* hfin = hbio[N_LAYERS & 1];

    hipMemsetAsync(out, 0, HIDDEN * sizeof(float), stream);
    reduce_kernel<<<1024, HIDDEN, 0, stream>>>(hfin, out);
}

// Round 18
// 763.241 us; speedup vs baseline: 1.2142x; 1.1128x over previous
//
#include <hip/hip_runtime.h>

#define N_NODES 100000
#define N_REL 4
#define N_EDGES 800000
#define HIDDEN 128
#define N_LAYERS 3

#define NBUCK 196   // ceil(100000/512) buckets of 512 nodes
#define NBB 196     // ceil(800000/4096) edge blocks
#define EPB 4096    // edges per bin block
#define BMAX 8192   // bucket_sort LDS staging capacity (mean 4082, std 64)

typedef __attribute__((ext_vector_type(8))) short short8;
typedef __attribute__((ext_vector_type(4))) float f32x4;

__device__ __forceinline__ unsigned short f2bf(float f) {
    unsigned u = __float_as_uint(f);
    u = (u + 0x7fffu + ((u >> 16) & 1u)) >> 16;
    return (unsigned short)u;
}
__device__ __forceinline__ float bf2f(unsigned short b) {
    return __uint_as_float(((unsigned)b) << 16);
}
// tanh(x) = 1 - 2/(e^{2x}+1), e = 2^(2*log2e*x). NaN-safe: e->inf => 1; e->0 => -1.
__device__ __forceinline__ float ftanh(float x) {
    float e = exp2f(2.8853900817779268f * x);
    return 1.0f - __fdividef(2.0f, e + 1.0f);
}

// ==================== CSR build: two-level bucketed counting sort ====================

__global__ __launch_bounds__(256) void bin_hist(const int* __restrict__ ei, int* __restrict__ bh) {
    __shared__ int hist[NBUCK];
    int r = blockIdx.y, blk = blockIdx.x, tid = threadIdx.x;
    for (int i = tid; i < NBUCK; i += 256) hist[i] = 0;
    __syncthreads();
    const int* dst = ei + (size_t)r * 2 * N_EDGES + N_EDGES;
#pragma unroll
    for (int i = 0; i < EPB / 256; ++i) {
        int e = blk * EPB + i * 256 + tid;
        if (e < N_EDGES) atomicAdd(&hist[dst[e] >> 9], 1);
    }
    __syncthreads();
    for (int i = tid; i < NBUCK; i += 256)
        bh[((size_t)r * NBUCK + i) * NBB + blk] = hist[i];
}

__global__ __launch_bounds__(256) void bin_scan(int* __restrict__ bh, int* __restrict__ btot) {
    __shared__ int sa[256], sb[256];
    int r = blockIdx.y, b = blockIdx.x, tid = threadIdx.x;
    int* row = bh + ((size_t)r * NBUCK + b) * NBB;
    int v = (tid < NBB) ? row[tid] : 0;
    sa[tid] = v;
    __syncthreads();
    int* pin = sa;
    int* pout = sb;
    for (int off = 1; off < 256; off <<= 1) {
        pout[tid] = pin[tid] + ((tid >= off) ? pin[tid - off] : 0);
        __syncthreads();
        int* t = pin; pin = pout; pout = t;
    }
    if (tid < NBB) row[tid] = pin[tid] - v;
    if (tid == NBB - 1) btot[r * NBUCK + b] = pin[tid];
}

__global__ void bin_base(const int* __restrict__ btot, int* __restrict__ bbase,
                         int* __restrict__ rowptr) {
    int r = threadIdx.x;
    if (r >= N_REL) return;
    int acc = 0;
    for (int b = 0; b < NBUCK; ++b) {
        bbase[r * (NBUCK + 1) + b] = acc;
        acc += btot[r * NBUCK + b];
    }
    bbase[r * (NBUCK + 1) + NBUCK] = acc;  // == N_EDGES
    rowptr[(size_t)r * (N_NODES + 1) + N_NODES] = N_EDGES;
}

__global__ __launch_bounds__(256) void bin_scatter(const int* __restrict__ ei,
                                                   const int* __restrict__ bh,
                                                   const int* __restrict__ bbase,
                                                   unsigned* __restrict__ staging) {
    __shared__ int hist[NBUCK];
    __shared__ int runStart[NBUCK + 1];
    __shared__ int runBaseG[NBUCK];
    __shared__ int curs[NBUCK];
    __shared__ unsigned packed[EPB];
    __shared__ int sa[256], sb[256];
    int r = blockIdx.y, blk = blockIdx.x, tid = threadIdx.x;
    const int* src = ei + (size_t)r * 2 * N_EDGES;
    const int* dst = src + N_EDGES;
    int e0 = blk * EPB;
    int ecnt = min(EPB, N_EDGES - e0);
    for (int i = tid; i < NBUCK; i += 256) hist[i] = 0;
    __syncthreads();
#pragma unroll
    for (int i = 0; i < EPB / 256; ++i) {
        int e = e0 + i * 256 + tid;
        if (e < N_EDGES) atomicAdd(&hist[dst[e] >> 9], 1);
    }
    __syncthreads();
    int v = (tid < NBUCK) ? hist[tid] : 0;
    sa[tid] = v;
    __syncthreads();
    int* pin = sa;
    int* pout = sb;
    for (int off = 1; off < 256; off <<= 1) {
        pout[tid] = pin[tid] + ((tid >= off) ? pin[tid - off] : 0);
        __syncthreads();
        int* t = pin; pin = pout; pout = t;
    }
    if (tid < NBUCK) {
        runStart[tid] = pin[tid] - v;
        curs[tid] = 0;
        runBaseG[tid] = bbase[r * (NBUCK + 1) + tid] + bh[((size_t)r * NBUCK + tid) * NBB + blk];
    }
    if (tid == 0) runStart[NBUCK] = ecnt;
    __syncthreads();
#pragma unroll
    for (int i = 0; i < EPB / 256; ++i) {
        int e = e0 + i * 256 + tid;
        if (e < N_EDGES) {
            int d = dst[e];
            int b = d >> 9;
            int lp = runStart[b] + atomicAdd(&curs[b], 1);
            packed[lp] = ((unsigned)(d & 511) << 17) | (unsigned)src[e];
        }
    }
    __syncthreads();
    for (int i = tid; i < ecnt; i += 256) {
        int lo = 0, hi = NBUCK;
        while (hi - lo > 1) {
            int mid = (lo + hi) >> 1;
            if (runStart[mid] <= i) lo = mid;
            else hi = mid;
        }
        staging[(size_t)r * N_EDGES + runBaseG[lo] + (i - runStart[lo])] = packed[i];
    }
}

__global__ __launch_bounds__(512) void bucket_sort(const unsigned* __restrict__ staging,
                                                   const int* __restrict__ bbase,
                                                   int* __restrict__ rowptr, int* __restrict__ cnt,
                                                   int* __restrict__ ssorted) {
    __shared__ int c512[512];
    __shared__ int lrp[512];
    __shared__ int curs[512];
    __shared__ int sb2[512];
    __shared__ int outbuf[BMAX];
    int r = blockIdx.y, b = blockIdx.x, tid = threadIdx.x;
    int base = bbase[r * (NBUCK + 1) + b];
    int total = bbase[r * (NBUCK + 1) + b + 1] - base;
    const unsigned* st = staging + (size_t)r * N_EDGES + base;
    c512[tid] = 0;
    __syncthreads();
    for (int i = tid; i < total; i += 512) atomicAdd(&c512[st[i] >> 17], 1);
    __syncthreads();
    int v = c512[tid];
    lrp[tid] = v;
    __syncthreads();
    int* pin = lrp;
    int* pout = sb2;
    for (int off = 1; off < 512; off <<= 1) {
        pout[tid] = pin[tid] + ((tid >= off) ? pin[tid - off] : 0);
        __syncthreads();
        int* t = pin; pin = pout; pout = t;
    }
    int excl = pin[tid] - v;
    __syncthreads();
    lrp[tid] = excl;
    curs[tid] = 0;
    int node = b * 512 + tid;
    if (node < N_NODES) {
        rowptr[(size_t)r * (N_NODES + 1) + node] = base + excl;
        cnt[(size_t)r * N_NODES + node] = v;
    }
    __syncthreads();
    if (total <= BMAX) {
        for (int i = tid; i < total; i += 512) {
            unsigned p = st[i];
            int dl = p >> 17;
            int pos = lrp[dl] + atomicAdd(&curs[dl], 1);
            outbuf[pos] = (int)(p & 0x1FFFFu);
        }
        __syncthreads();
        for (int i = tid; i < total; i += 512)
            ssorted[(size_t)r * N_EDGES + base + i] = outbuf[i];
    } else {
        for (int i = tid; i < total; i += 512) {
            unsigned p = st[i];
            int dl = p >> 17;
            int pos = lrp[dl] + atomicAdd(&curs[dl], 1);
            ssorted[(size_t)r * N_EDGES + base + pos] = (int)(p & 0x1FFFFu);
        }
    }
}

// ==================== dense pipeline ====================

__global__ void prepw_kernel(const float* __restrict__ Wbr, const float* __restrict__ Wcb,
                             unsigned short* __restrict__ WTh, unsigned short* __restrict__ WTl) {
    int t = blockIdx.x * blockDim.x + threadIdx.x;
    if (t >= 15 * HIDDEN * HIDDEN) return;
    int m = t >> 14;
    int j = (t >> 7) & 127;
    int k = t & 127;
    float v = (m < 12) ? Wbr[((size_t)m << 14) + k * HIDDEN + j]
                       : Wcb[((size_t)(m - 12) << 14) + k * HIDDEN + j];
    unsigned short hb = f2bf(v);
    WTh[t] = hb;
    WTl[t] = f2bf(v - bf2f(hb));
}

__global__ void hinit_kernel(const int* __restrict__ cnt, const float* __restrict__ Win,
                             unsigned short* __restrict__ hb) {
    int t = blockIdx.x * blockDim.x + threadIdx.x;
    if (t >= N_NODES * 16) return;
    int n = t >> 4, jq = (t & 15) * 8;
    float c0 = (float)cnt[n];
    float c1 = (float)cnt[N_NODES + n];
    float c2 = (float)cnt[2 * N_NODES + n];
    float c3 = (float)cnt[3 * N_NODES + n];
    short8 ob;
#pragma unroll
    for (int i = 0; i < 8; ++i) {
        int j = jq + i;
        float s = c0 * Win[j] + c1 * Win[HIDDEN + j] + c2 * Win[2 * HIDDEN + j] +
                  c3 * Win[3 * HIDDEN + j];
        ob[i] = (short)f2bf(ftanh(s));
    }
    *(short8*)(hb + (size_t)n * HIDDEN + jq) = ob;
}

// ---- gather: agg[r][n] = sum_{e in CSR row n of rel r} h[src[e]]; bf16 in/out ----
// R15 config: 16 lanes/node x 4 nodes/wave x 4-edge unroll = 16 loads in flight/wave.
// (R16 one-node/wave lost MLP; R17 degree-sort lost locality — both regressed.)
__global__ __launch_bounds__(256) void gather_kernel(
    const int* __restrict__ rowptr, const int* __restrict__ ssorted,
    const unsigned short* __restrict__ hinb, unsigned short* __restrict__ agg) {
    const int r = blockIdx.y;
    const int node = blockIdx.x * 16 + (threadIdx.x >> 4);
    const int l16 = threadIdx.x & 15;
    if (node >= N_NODES) return;
    const int* rp = rowptr + (size_t)r * (N_NODES + 1);
    int beg = rp[node], end = rp[node + 1];
    const int* ss = ssorted + (size_t)r * N_EDGES;
    float acc[8];
#pragma unroll
    for (int i = 0; i < 8; ++i) acc[i] = 0.f;
    int e = beg;
    for (; e + 3 < end; e += 4) {
        int s0 = ss[e], s1 = ss[e + 1], s2 = ss[e + 2], s3 = ss[e + 3];
        uint4 v0 = *((const uint4*)(hinb + (size_t)s0 * HIDDEN) + l16);
        uint4 v1 = *((const uint4*)(hinb + (size_t)s1 * HIDDEN) + l16);
        uint4 v2 = *((const uint4*)(hinb + (size_t)s2 * HIDDEN) + l16);
        uint4 v3 = *((const uint4*)(hinb + (size_t)s3 * HIDDEN) + l16);
        unsigned a0[4] = {v0.x, v0.y, v0.z, v0.w};
        unsigned a1[4] = {v1.x, v1.y, v1.z, v1.w};
        unsigned a2[4] = {v2.x, v2.y, v2.z, v2.w};
        unsigned a3[4] = {v3.x, v3.y, v3.z, v3.w};
#pragma unroll
        for (int c = 0; c < 4; ++c) {
            acc[c * 2] += (__uint_as_float(a0[c] << 16) + __uint_as_float(a1[c] << 16)) +
                          (__uint_as_float(a2[c] << 16) + __uint_as_float(a3[c] << 16));
            acc[c * 2 + 1] +=
                (__uint_as_float(a0[c] & 0xffff0000u) + __uint_as_float(a1[c] & 0xffff0000u)) +
                (__uint_as_float(a2[c] & 0xffff0000u) + __uint_as_float(a3[c] & 0xffff0000u));
        }
    }
    for (; e < end; ++e) {
        int s0 = ss[e];
        uint4 v0 = *((const uint4*)(hinb + (size_t)s0 * HIDDEN) + l16);
        unsigned a0[4] = {v0.x, v0.y, v0.z, v0.w};
#pragma unroll
        for (int c = 0; c < 4; ++c) {
            acc[c * 2] += __uint_as_float(a0[c] << 16);
            acc[c * 2 + 1] += __uint_as_float(a0[c] & 0xffff0000u);
        }
    }
    short8 pk;
#pragma unroll
    for (int c = 0; c < 8; ++c) pk[c] = (short)f2bf(acc[c]);
    *(short8*)(agg + ((size_t)r * N_NODES + node) * HIDDEN + l16 * 8) = pk;
}

// ---- GEMM: h_out = tanh( (h_in + sum_r tanh(agg_r @ Wb_r)) @ Wc ), 64 nodes/block ----
// 512 threads, 8 waves = 8 COLUMN slices (16 cols each); weight fragments disjoint
// per wave; 4 relation tiles staged into 64 KB LDS behind ONE barrier.
__global__ __launch_bounds__(512) void gemm_kernel(
    const unsigned short* __restrict__ agg,         // [4][N][128] bf16
    const unsigned short* __restrict__ hinb,        // [N][128] bf16
    unsigned short* __restrict__ houtb,             // [N][128] bf16
    const unsigned short* __restrict__ WTbh,        // [4][128][128] bf16 hi, [col][k]
    const unsigned short* __restrict__ WTbl,        // [4][128][128] bf16 lo
    const unsigned short* __restrict__ WTch,        // [128][128] bf16 hi
    const unsigned short* __restrict__ WTcl) {      // [128][128] bf16 lo
    __shared__ unsigned short atile[4 * 64 * HIDDEN];  // 4 x 16 KB swizzled tiles
    const int tid = threadIdx.x;
    const int n0 = blockIdx.x * 64;
    const int lane = tid & 63;
    const int lrow = lane & 15;
    const int lk = lane >> 4;
    const int wv = tid >> 6;        // 0..7
    const int wcol = wv * 16;       // this wave's 16 output columns
    const int asw = (lrow & 7) << 4;

    const int gn = tid >> 3;        // staging: local node 0..63
    const int gq = tid & 7;         // staging: 32B chunk 0..7
    const int gnode = n0 + gn;
    const int grsw = (gn & 7) << 4;
    const bool gok = (gnode < N_NODES);

    // ---- stage ALL 4 relation tiles (swizzled); single barrier after ----
#pragma unroll
    for (int r = 0; r < N_REL; ++r) {
        const uint4* ap = (const uint4*)(agg + ((size_t)r * N_NODES + gnode) * HIDDEN) + gq * 2;
        uint4 s0 = gok ? ap[0] : uint4{0u, 0u, 0u, 0u};
        uint4 s1 = gok ? ap[1] : uint4{0u, 0u, 0u, 0u};
        char* tb = (char*)atile + r * 16384 + gn * 256;
        *(uint4*)(tb + ((gq * 32 + 0) ^ grsw)) = s0;
        *(uint4*)(tb + ((gq * 32 + 16) ^ grsw)) = s1;
    }

    // comb init (independent global loads; overlap with staging)
    float comb[4][4];
#pragma unroll
    for (int rt = 0; rt < 4; ++rt)
#pragma unroll
        for (int j = 0; j < 4; ++j) {
            int node = n0 + rt * 16 + lk * 4 + j;
            int col = wcol + lrow;
            comb[rt][j] = (node < N_NODES) ? bf2f(hinb[(size_t)node * HIDDEN + col]) : 0.f;
        }

    __syncthreads();

    // ---- 4 branch MFMA phases, barrier-free ----
#pragma unroll
    for (int r = 0; r < N_REL; ++r) {
        const unsigned short* Wh = WTbh + ((size_t)r << 14);
        const unsigned short* Wl = WTbl + ((size_t)r << 14);
        const char* tb = (const char*)atile + r * 16384;
        f32x4 macc[4];
#pragma unroll
        for (int rt = 0; rt < 4; ++rt) macc[rt] = f32x4{0.f, 0.f, 0.f, 0.f};
#pragma unroll
        for (int kb = 0; kb < 4; ++kb) {
            int wo = (wcol + lrow) * HIDDEN + kb * 32 + lk * 8;
            short8 bh = *(const short8*)(Wh + wo);
            short8 bl = *(const short8*)(Wl + wo);
#pragma unroll
            for (int rt = 0; rt < 4; ++rt) {
                int ao = (rt * 16 + lrow) * 256 + ((kb * 64 + lk * 16) ^ asw);
                short8 ah = *(const short8*)(tb + ao);
                macc[rt] = __builtin_amdgcn_mfma_f32_16x16x32_bf16(ah, bh, macc[rt], 0, 0, 0);
                macc[rt] = __builtin_amdgcn_mfma_f32_16x16x32_bf16(ah, bl, macc[rt], 0, 0, 0);
            }
        }
#pragma unroll
        for (int rt = 0; rt < 4; ++rt)
#pragma unroll
            for (int j = 0; j < 4; ++j) comb[rt][j] += ftanh(macc[rt][j]);
    }

    // ---- combine: comb -> hi tile only (tile 0), swizzled ----
    __syncthreads();
#pragma unroll
    for (int rt = 0; rt < 4; ++rt)
#pragma unroll
        for (int j = 0; j < 4; ++j) {
            int row = rt * 16 + lk * 4 + j;
            int col = wcol + lrow;
            int byt = row * 256 + ((col * 2) ^ ((row & 7) << 4));
            *(unsigned short*)((char*)atile + byt) = f2bf(comb[rt][j]);
        }
    __syncthreads();

    f32x4 macc[4];
#pragma unroll
    for (int rt = 0; rt < 4; ++rt) macc[rt] = f32x4{0.f, 0.f, 0.f, 0.f};
#pragma unroll
    for (int kb = 0; kb < 4; ++kb) {
        int wo = (wcol + lrow) * HIDDEN + kb * 32 + lk * 8;
        short8 bh = *(const short8*)(WTch + wo);
        short8 bl = *(const short8*)(WTcl + wo);
#pragma unroll
        for (int rt = 0; rt < 4; ++rt) {
            int ao = (rt * 16 + lrow) * 256 + ((kb * 64 + lk * 16) ^ asw);
            short8 ah = *(const short8*)((const char*)atile + ao);
            macc[rt] = __builtin_amdgcn_mfma_f32_16x16x32_bf16(ah, bh, macc[rt], 0, 0, 0);
            macc[rt] = __builtin_amdgcn_mfma_f32_16x16x32_bf16(ah, bl, macc[rt], 0, 0, 0);
        }
    }
#pragma unroll
    for (int rt = 0; rt < 4; ++rt)
#pragma unroll
        for (int j = 0; j < 4; ++j) {
            int node = n0 + rt * 16 + lk * 4 + j;
            if (node < N_NODES)
                houtb[(size_t)node * HIDDEN + wcol + lrow] = f2bf(ftanh(macc[rt][j]));
        }
}

// ---- out[j] = sum_n h[n][j] (bf16 in, f32 out) ----
__global__ void reduce_kernel(const unsigned short* __restrict__ h, float* __restrict__ out) {
    int j = threadIdx.x;
    float s = 0.f;
    for (int n = blockIdx.x; n < N_NODES; n += gridDim.x)
        s += bf2f(h[(size_t)n * HIDDEN + j]);
    atomicAdd(&out[j], s);
}

extern "C" void kernel_launch(void* const* d_in, const int* in_sizes, int n_in,
                              void* d_out, int out_size, void* d_ws, size_t ws_size,
                              hipStream_t stream) {
    const int* ei = (const int*)d_in[0];
    const float* Win = (const float*)d_in[1];
    const float* Wbr = (const float*)d_in[2];
    const float* Wcb = (const float*)d_in[3];
    float* out = (float*)d_out;

    char* p = (char*)d_ws;
    auto alloc = [&](size_t bytes) {
        char* q = p;
        p += (bytes + 511) & ~(size_t)511;
        return q;
    };
    int* cnt = (int*)alloc((size_t)N_REL * N_NODES * 4);
    int* rowptr = (int*)alloc((size_t)N_REL * (N_NODES + 1) * 4);
    int* ssorted = (int*)alloc((size_t)N_REL * N_EDGES * 4);
    unsigned* staging = (unsigned*)alloc((size_t)N_REL * N_EDGES * 4);
    int* bh = (int*)alloc((size_t)N_REL * NBUCK * NBB * 4);
    int* btot = (int*)alloc((size_t)N_REL * NBUCK * 4);
    int* bbase = (int*)alloc((size_t)N_REL * (NBUCK + 1) * 4);
    unsigned short* WTh = (unsigned short*)alloc((size_t)15 * HIDDEN * HIDDEN * 2);
    unsigned short* WTl = (unsigned short*)alloc((size_t)15 * HIDDEN * HIDDEN * 2);
    unsigned short* hb0 = (unsigned short*)alloc((size_t)N_NODES * HIDDEN * 2);
    unsigned short* hb1 = (unsigned short*)alloc((size_t)N_NODES * HIDDEN * 2);
    unsigned short* agg = (unsigned short*)alloc((size_t)N_REL * N_NODES * HIDDEN * 2);

    // ---- CSR build (bucketed counting sort; also emits cnt = degrees) ----
    dim3 bg(NBB, N_REL);
    bin_hist<<<bg, 256, 0, stream>>>(ei, bh);
    dim3 sg(NBUCK, N_REL);
    bin_scan<<<sg, 256, 0, stream>>>(bh, btot);
    bin_base<<<1, 64, 0, stream>>>(btot, bbase, rowptr);
    bin_scatter<<<bg, 256, 0, stream>>>(ei, bh, bbase, staging);
    bucket_sort<<<sg, 512, 0, stream>>>(staging, bbase, rowptr, cnt, ssorted);

    // ---- weights + h0 ----
    prepw_kernel<<<(15 * HIDDEN * HIDDEN + 255) / 256, 256, 0, stream>>>(Wbr, Wcb, WTh, WTl);
    hinit_kernel<<<(N_NODES * 16 + 255) / 256, 256, 0, stream>>>(cnt, Win, hb0);

    // ---- layers: gather (per relation) + fused GEMM ----
    dim3 gg((N_NODES + 15) / 16, N_REL);
    int cgrid = (N_NODES + 63) / 64;
    unsigned short* hbio[2] = {hb0, hb1};
    for (int l = 0; l < N_LAYERS; ++l) {
        int a = l & 1, b = a ^ 1;
        gather_kernel<<<gg, 256, 0, stream>>>(rowptr, ssorted, hbio[a], agg);
        gemm_kernel<<<cgrid, 512, 0, stream>>>(
            agg, hbio[a], hbio[b],
            WTh + (size_t)(l * 4) * HIDDEN * HIDDEN, WTl + (size_t)(l * 4) * HIDDEN * HIDDEN,
            WTh + (size_t)(12 + l) * HIDDEN * HIDDEN, WTl + (size_t)(12 + l) * HIDDEN * HIDDEN);
    }
    unsigned short* hfin = hbio[N_LAYERS & 1];

    hipMemsetAsync(out, 0, HIDDEN * sizeof(float), stream);
    reduce_kernel<<<1024, HIDDEN, 0, stream>>>(hfin, out);
}